// Round 7
// baseline (405.871 us; speedup 1.0000x reference)
//
#include <hip/hip_runtime.h>
#include <hip/hip_bf16.h>

#define D  128
#define KN 32

typedef __attribute__((ext_vector_type(8))) short bf16x8;
typedef __attribute__((ext_vector_type(4))) float f32x4;

static __device__ __forceinline__ unsigned short f2bf(float f) {
    union { float f; unsigned int u; } v; v.f = f;
    unsigned int u = v.u;
    u += 0x7fff + ((u >> 16) & 1);   // round-to-nearest-even
    return (unsigned short)(u >> 16);
}
static __device__ __forceinline__ float bf2f(unsigned short h) {
    union { float f; unsigned int u; } v; v.u = ((unsigned int)h) << 16;
    return v.f;
}

// One-shot: transpose+convert W1 halves and W2 into bf16 [col][k] layouts.
__global__ __launch_bounds__(256) void wt_kernel(
    const float* __restrict__ W1, const float* __restrict__ W2,
    unsigned short* __restrict__ W1Tt, unsigned short* __restrict__ W1Tb,
    unsigned short* __restrict__ W2T)
{
    int idx = blockIdx.x * 256 + threadIdx.x;
    if (idx < D * D) {
        int col = idx >> 7, e = idx & 127;
        W1Tt[col * D + e] = f2bf(W1[e * D + col]);
        W1Tb[col * D + e] = f2bf(W1[(D + e) * D + col]);
        W2T [col * D + e] = f2bf(W2[e * D + col]);
    }
}

// Fused P1/Q producer (round-3-verified version: restaged epilogue with
// fully-contiguous 4KB-per-instruction stores for EB, P1 and Q).
// Blocks [0,nvBlocks): P1 = emb@W1top (+ bf16 emb copy EB).
// Blocks [nvBlocks,..): Q = emb[vnodes]@W1bot + b1.
__global__ __launch_bounds__(256) void p1q_kernel(
    const float* __restrict__ emb, const int* __restrict__ vnodes,
    int NV, int NN, int nvBlocks,
    const unsigned short* __restrict__ W1Tt, const unsigned short* __restrict__ W1Tb,
    const float* __restrict__ b1,
    unsigned short* __restrict__ P1, unsigned short* __restrict__ Q,
    unsigned short* __restrict__ EB)
{
    __shared__ unsigned short sA[128][136];

    const int tid  = threadIdx.x;
    const int lane = tid & 63;
    const int w    = tid >> 6;
    const int m    = lane & 15, q = lane >> 4;

    const bool nv = (int)blockIdx.x < nvBlocks;
    const int  bi = nv ? blockIdx.x : blockIdx.x - nvBlocks;
    const int  M  = nv ? NV : NN;
    const unsigned short* WT = nv ? W1Tt : W1Tb;
    const int r0 = bi * 128;

    int maxRows = M - r0; if (maxRows > 128) maxRows = 128;
    const int maxB = maxRows << 8;          // valid bytes in this block's region

    // stage 128 rows fp32->bf16 (coalesced float4 stream / gather)
#pragma unroll
    for (int i = 0; i < 16; ++i) {
        int e = tid + 256 * i;
        int row = e >> 5, c4 = (e & 31) << 2;
        int r = r0 + row; if (r > M - 1) r = M - 1;
        int vr = nv ? r : vnodes[r];
        const float4 f = *(const float4*)(emb + (long)vr * D + c4);
        ushort4 h;
        h.x = f2bf(f.x); h.y = f2bf(f.y); h.z = f2bf(f.z); h.w = f2bf(f.w);
        *(ushort4*)(&sA[row][c4]) = h;
    }
    __syncthreads();

    // EB emission (pre-restage sA): fully-contiguous 4KB per instruction
    if (nv) {
        char* ebBase = (char*)(EB + (long)r0 * D);
#pragma unroll
        for (int j = 0; j < 8; ++j) {
            int p = j * 4096 + tid * 16;
            if (p < maxB) {
                int row = p >> 8, off = (p & 255) >> 1;
                *(bf16x8*)(ebBase + p) = *(const bf16x8*)(&sA[row][off]);
            }
        }
    }

    bf16x8 Bf[2][4];
#pragma unroll
    for (int nt = 0; nt < 2; ++nt)
#pragma unroll
        for (int kk = 0; kk < 4; ++kk)
            Bf[nt][kk] = *(const bf16x8*)(WT + (32 * w + 16 * nt + m) * D + kk * 32 + q * 8);
    float bv[2];
#pragma unroll
    for (int nt = 0; nt < 2; ++nt) bv[nt] = nv ? 0.f : b1[32 * w + 16 * nt + m];

    f32x4 acc[8][2];
#pragma unroll
    for (int mt = 0; mt < 8; ++mt)
#pragma unroll
        for (int nt = 0; nt < 2; ++nt) acc[mt][nt] = (f32x4){0.f, 0.f, 0.f, 0.f};

#pragma unroll
    for (int kk = 0; kk < 4; ++kk) {
#pragma unroll
        for (int mt = 0; mt < 8; ++mt) {
            bf16x8 a = *(const bf16x8*)(&sA[16 * mt + m][kk * 32 + q * 8]);
            acc[mt][0] = __builtin_amdgcn_mfma_f32_16x16x32_bf16(a, Bf[0][kk], acc[mt][0], 0, 0, 0);
            acc[mt][1] = __builtin_amdgcn_mfma_f32_16x16x32_bf16(a, Bf[1][kk], acc[mt][1], 0, 0, 0);
        }
    }

    // ---- restage C into sA, then fully-contiguous 4KB stores ----
    __syncthreads();   // all A-reads + EB-reads of sA complete
    // C/D layout: col=lane&15, row=(lane>>4)*4+reg
#pragma unroll
    for (int mt = 0; mt < 8; ++mt)
#pragma unroll
        for (int nt = 0; nt < 2; ++nt) {
            int col = 32 * w + 16 * nt + m;
#pragma unroll
            for (int r = 0; r < 4; ++r)
                sA[16 * mt + 4 * q + r][col] = f2bf(acc[mt][nt][r] + bv[nt]);
        }
    __syncthreads();
    {
        char* dstBase = (char*)((nv ? P1 : Q) + (long)r0 * D);
#pragma unroll
        for (int j = 0; j < 8; ++j) {
            int p = j * 4096 + tid * 16;
            if (p < maxB) {
                int row = p >> 8, off = (p & 255) >> 1;
                *(bf16x8*)(dstBase + p) = *(const bf16x8*)(&sA[row][off]);
            }
        }
    }
}

// Fused per-node aggregator (round-6-verified structure, occupancy bump).
// Round-6 measured: VGPR_Count=104, LDS=37376 -> fits 4 blocks/CU under the
// (256,4) 128-reg cap (104<=128; 4x37376=149.5KB<160KB). Doubles waves/CU
// 8 -> 16 to double outstanding gather requests; everything else identical.
__global__ __launch_bounds__(256, 4) void agg_kernel(
    const unsigned short* __restrict__ EB, const int* __restrict__ nidx,
    const unsigned short* __restrict__ W2T, const float* __restrict__ b2,
    const float* __restrict__ W3, const float* __restrict__ b3,
    const unsigned short* __restrict__ P1, const unsigned short* __restrict__ Q,
    float* __restrict__ out, int NN)
{
    __shared__ unsigned short sX[128][136];
    __shared__ float sSp[4][128];
    __shared__ float sAtt[128];

    const int tid  = threadIdx.x;
    const int lane = tid & 63;
    const int w    = tid >> 6;          // wave index == node sub-index
    const int m    = lane & 15, q = lane >> 4;
    const int g4   = q;                 // row-group within wave
    const int c    = m;                 // 16B chunk within row

    // register-resident B fragments (W2T), per-wave 32-col slice
    bf16x8 Bf[2][4];
#pragma unroll
    for (int nt = 0; nt < 2; ++nt)
#pragma unroll
        for (int kk = 0; kk < 4; ++kk)
            Bf[nt][kk] = *(const bf16x8*)(W2T + (32 * w + 16 * nt + m) * D + kk * 32 + q * 8);
    float b2v[2], w3v[2];
#pragma unroll
    for (int nt = 0; nt < 2; ++nt) {
        int col = 32 * w + 16 * nt + m;
        b2v[nt] = b2[col];
        w3v[nt] = W3[col];
    }
    const float b3s = b3[0];

    const int groups = (NN + 3) >> 2;

    // ---- pipeline prologue: group blockIdx.x ----
    int g = blockIdx.x;
    int ni[8];          // neighbor indices, k = 4j+g4 (uniform per 16-lane group)
    bf16x8 pf[8];       // P1 row fragments: pf[j] = P1[ni[j]][c*8 .. +8]
    if (g < groups) {
        int nd = g * 4 + w; if (nd > NN - 1) nd = NN - 1;
#pragma unroll
        for (int j = 0; j < 8; ++j) {
            ni[j] = nidx[nd * KN + 4 * j + g4];
            pf[j] = *(const bf16x8*)(P1 + (long)ni[j] * D + c * 8);
        }
    }

    for (; g < groups; g += gridDim.x) {
        const int node0 = g * 4;
        int nd = node0 + w; if (nd > NN - 1) nd = NN - 1;

        // ---- EB gather for current group at iteration top (4x256B/inst,
        //      consumed at iteration end: full iteration to hide) ----
        bf16x8 gv[8];
#pragma unroll
        for (int j = 0; j < 8; ++j)
            gv[j] = *(const bf16x8*)(EB + (long)ni[j] * D + c * 8);

        // ---- convert+store X = relu(pf + Q[nd]) into wave-private rows ----
        {
            const bf16x8 qv = *(const bf16x8*)(Q + (long)nd * D + c * 8);
#pragma unroll
            for (int j = 0; j < 8; ++j) {
                bf16x8 r;
#pragma unroll
                for (int h = 0; h < 8; ++h) {
                    float v = bf2f((unsigned short)pf[j][h]) + bf2f((unsigned short)qv[h]);
                    r[h] = (short)f2bf(v > 0.f ? v : 0.f);
                }
                *(bf16x8*)(&sX[w * 32 + 4 * j + g4][c * 8]) = r;
            }
        }

        // ---- next-group indices (same-address loads per 16-lane group) ----
        const int gn = g + gridDim.x;
        const bool more = gn < groups;
        int nin[8];
        if (more) {
            int ndn = gn * 4 + w; if (ndn > NN - 1) ndn = NN - 1;
#pragma unroll
            for (int j = 0; j < 8; ++j) nin[j] = nidx[ndn * KN + 4 * j + g4];
        }
        __syncthreads();   // sX ready for all waves

        // ---- P1 prefetch for NEXT group (in flight during compute) ----
        if (more) {
#pragma unroll
            for (int j = 0; j < 8; ++j)
                pf[j] = *(const bf16x8*)(P1 + (long)nin[j] * D + c * 8);
        }

        // ---- layer-2 GEMM in 2 halves of 4 M-tiles (acc = 32 regs) ----
#pragma unroll
        for (int hv = 0; hv < 2; ++hv) {
            f32x4 acc[4][2];
#pragma unroll
            for (int mt = 0; mt < 4; ++mt) {
                acc[mt][0] = (f32x4){0.f, 0.f, 0.f, 0.f};
                acc[mt][1] = (f32x4){0.f, 0.f, 0.f, 0.f};
            }
#pragma unroll
            for (int kk = 0; kk < 4; ++kk) {
#pragma unroll
                for (int mt = 0; mt < 4; ++mt) {
                    bf16x8 a = *(const bf16x8*)(&sX[16 * (4 * hv + mt) + m][kk * 32 + q * 8]);
                    acc[mt][0] = __builtin_amdgcn_mfma_f32_16x16x32_bf16(a, Bf[0][kk], acc[mt][0], 0, 0, 0);
                    acc[mt][1] = __builtin_amdgcn_mfma_f32_16x16x32_bf16(a, Bf[1][kk], acc[mt][1], 0, 0, 0);
                }
            }
            // scores for these 4 M-tiles: relu+bias, dot W3, reduce 16 lanes
#pragma unroll
            for (int mt = 0; mt < 4; ++mt) {
                float p[4];
#pragma unroll
                for (int r = 0; r < 4; ++r) {
                    float h0 = acc[mt][0][r] + b2v[0]; h0 = h0 > 0.f ? h0 : 0.f;
                    float h1 = acc[mt][1][r] + b2v[1]; h1 = h1 > 0.f ? h1 : 0.f;
                    p[r] = h0 * w3v[0] + h1 * w3v[1];
                }
#pragma unroll
                for (int off = 8; off >= 1; off >>= 1)
#pragma unroll
                    for (int r = 0; r < 4; ++r) p[r] += __shfl_xor(p[r], off, 16);
                if (m == 0) {
#pragma unroll
                    for (int r = 0; r < 4; ++r) sSp[w][16 * (4 * hv + mt) + 4 * q + r] = p[r];
                }
            }
        }
        __syncthreads();

        // ---- softmax: 128 scores = 4 nodes x 32 neighbors ----
        if (tid < 128) {
            float s = sSp[0][tid] + sSp[1][tid] + sSp[2][tid] + sSp[3][tid] + b3s;
            float mx = s;
#pragma unroll
            for (int off = 16; off >= 1; off >>= 1) mx = fmaxf(mx, __shfl_xor(mx, off, 32));
            float e = __expf(s - mx);
            float sum = e;
#pragma unroll
            for (int off = 16; off >= 1; off >>= 1) sum += __shfl_xor(sum, off, 32);
            sAtt[tid] = e / sum;
        }
        __syncthreads();

        // ---- aggregation: node w per wave, from top-issued gv ----
        {
            float r8[8] = {0.f, 0.f, 0.f, 0.f, 0.f, 0.f, 0.f, 0.f};
#pragma unroll
            for (int j = 0; j < 8; ++j) {
                float a = sAtt[w * KN + 4 * j + g4];
#pragma unroll
                for (int h = 0; h < 8; ++h)
                    r8[h] += a * bf2f((unsigned short)gv[j][h]);
            }
#pragma unroll
            for (int h = 0; h < 8; ++h) {
                r8[h] += __shfl_xor(r8[h], 16);
                r8[h] += __shfl_xor(r8[h], 32);
            }
            int ndw = node0 + w;
            if (g4 == 0 && ndw < NN) {
                float4 o0 = {r8[0], r8[1], r8[2], r8[3]};
                float4 o1 = {r8[4], r8[5], r8[6], r8[7]};
                *(float4*)(out + (long)ndw * D + c * 8)     = o0;
                *(float4*)(out + (long)ndw * D + c * 8 + 4) = o1;
            }
        }
        // carry next-group indices (safe: loop exits when !more)
#pragma unroll
        for (int j = 0; j < 8; ++j) ni[j] = nin[j];
    }
}

// Correct-but-slow fp32 VALU fallback (only if ws is too small).
__global__ __launch_bounds__(128) void naive_kernel(
    const float* __restrict__ emb, const int* __restrict__ vnodes,
    const int* __restrict__ nidx,
    const float* __restrict__ W1, const float* __restrict__ b1,
    const float* __restrict__ W2, const float* __restrict__ b2,
    const float* __restrict__ W3, const float* __restrict__ b3,
    float* __restrict__ out)
{
    __shared__ float sE[KN + 1][D];
    __shared__ float sH[KN][D];
    __shared__ float sH2[KN][D];
    __shared__ float sS[KN];
    __shared__ float sA2[KN];
    const int node = blockIdx.x, tid = threadIdx.x;

    for (int r = 0; r < KN + 1; ++r) {
        int vr = (r < KN) ? nidx[node * KN + r] : vnodes[node];
        sE[r][tid] = emb[(long)vr * D + tid];
    }
    __syncthreads();
    for (int k = 0; k < KN; ++k) {
        float s = b1[tid];
        for (int e = 0; e < D; ++e) s += sE[k][e]  * W1[e * D + tid];
        for (int e = 0; e < D; ++e) s += sE[KN][e] * W1[(D + e) * D + tid];
        sH[k][tid] = s > 0.f ? s : 0.f;
    }
    __syncthreads();
    for (int k = 0; k < KN; ++k) {
        float s = b2[tid];
        for (int e = 0; e < D; ++e) s += sH[k][e] * W2[e * D + tid];
        sH2[k][tid] = s > 0.f ? s : 0.f;
    }
    __syncthreads();
    if (tid < KN) {
        float s = b3[0];
        for (int e = 0; e < D; ++e) s += sH2[tid][e] * W3[e];
        sS[tid] = s;
    }
    __syncthreads();
    if (tid == 0) {
        float mx = sS[0];
        for (int k = 1; k < KN; ++k) mx = fmaxf(mx, sS[k]);
        float sum = 0.f;
        for (int k = 0; k < KN; ++k) { sA2[k] = __expf(sS[k] - mx); sum += sA2[k]; }
        for (int k = 0; k < KN; ++k) sA2[k] /= sum;
    }
    __syncthreads();
    float a = 0.f;
    for (int k = 0; k < KN; ++k) a += sA2[k] * sE[k][tid];
    out[(long)node * D + tid] = a;
}

extern "C" void kernel_launch(void* const* d_in, const int* in_sizes, int n_in,
                              void* d_out, int out_size, void* d_ws, size_t ws_size,
                              hipStream_t stream) {
    const float* emb    = (const float*)d_in[0];
    const int*   vnodes = (const int*)d_in[1];
    const int*   nidx   = (const int*)d_in[2];
    const float* W1     = (const float*)d_in[3];
    const float* b1     = (const float*)d_in[4];
    const float* W2     = (const float*)d_in[5];
    const float* b2     = (const float*)d_in[6];
    const float* W3     = (const float*)d_in[7];
    const float* b3     = (const float*)d_in[8];
    float* out = (float*)d_out;

    const int NV = in_sizes[0] / D;   // 200000
    const int NN = in_sizes[1];       // 20000

    const size_t p1_elems = (size_t)NV * D;
    const size_t q_elems  = (size_t)NN * D;
    const size_t wt_elems = (size_t)D * D;
    const size_t need = (2 * p1_elems + q_elems + 3 * wt_elems) * sizeof(unsigned short);

    if (ws_size >= need) {
        unsigned short* P1   = (unsigned short*)d_ws;
        unsigned short* Q    = P1 + p1_elems;
        unsigned short* W1Tt = Q + q_elems;
        unsigned short* W1Tb = W1Tt + wt_elems;
        unsigned short* W2T  = W1Tb + wt_elems;
        unsigned short* EB   = W2T + wt_elems;

        const int nvBlocks = (NV + 127) / 128;
        const int qBlocks  = (NN + 127) / 128;

        wt_kernel<<<(D * D + 255) / 256, 256, 0, stream>>>(W1, W2, W1Tt, W1Tb, W2T);
        p1q_kernel<<<nvBlocks + qBlocks, 256, 0, stream>>>(
            emb, vnodes, NV, NN, nvBlocks, W1Tt, W1Tb, b1, P1, Q, EB);
        agg_kernel<<<1024, 256, 0, stream>>>(
            EB, nidx, W2T, b2, W3, b3, P1, Q, out, NN);
    } else {
        naive_kernel<<<NN, D, 0, stream>>>(emb, vnodes, nidx, W1, b1, W2, b2, W3, b3, out);
    }
}

// Round 8
// 310.475 us; speedup vs baseline: 1.3073x; 1.3073x over previous
//
#include <hip/hip_runtime.h>
#include <hip/hip_bf16.h>

#define D  128
#define KN 32

typedef __attribute__((ext_vector_type(8))) short bf16x8;
typedef __attribute__((ext_vector_type(4))) float f32x4;

static __device__ __forceinline__ unsigned short f2bf(float f) {
    union { float f; unsigned int u; } v; v.f = f;
    unsigned int u = v.u;
    u += 0x7fff + ((u >> 16) & 1);   // round-to-nearest-even
    return (unsigned short)(u >> 16);
}
static __device__ __forceinline__ float bf2f(unsigned short h) {
    union { float f; unsigned int u; } v; v.u = ((unsigned int)h) << 16;
    return v.f;
}

// One-shot: transpose+convert W1 halves and W2 into bf16 [col][k] layouts.
__global__ __launch_bounds__(256) void wt_kernel(
    const float* __restrict__ W1, const float* __restrict__ W2,
    unsigned short* __restrict__ W1Tt, unsigned short* __restrict__ W1Tb,
    unsigned short* __restrict__ W2T)
{
    int idx = blockIdx.x * 256 + threadIdx.x;
    if (idx < D * D) {
        int col = idx >> 7, e = idx & 127;
        W1Tt[col * D + e] = f2bf(W1[e * D + col]);
        W1Tb[col * D + e] = f2bf(W1[(D + e) * D + col]);
        W2T [col * D + e] = f2bf(W2[e * D + col]);
    }
}

// Fused P1/Q producer (round-3-verified version: restaged epilogue with
// fully-contiguous 4KB-per-instruction stores for EB, P1 and Q).
// Blocks [0,nvBlocks): P1 = emb@W1top (+ bf16 emb copy EB).
// Blocks [nvBlocks,..): Q = emb[vnodes]@W1bot + b1.
__global__ __launch_bounds__(256) void p1q_kernel(
    const float* __restrict__ emb, const int* __restrict__ vnodes,
    int NV, int NN, int nvBlocks,
    const unsigned short* __restrict__ W1Tt, const unsigned short* __restrict__ W1Tb,
    const float* __restrict__ b1,
    unsigned short* __restrict__ P1, unsigned short* __restrict__ Q,
    unsigned short* __restrict__ EB)
{
    __shared__ unsigned short sA[128][136];

    const int tid  = threadIdx.x;
    const int lane = tid & 63;
    const int w    = tid >> 6;
    const int m    = lane & 15, q = lane >> 4;

    const bool nv = (int)blockIdx.x < nvBlocks;
    const int  bi = nv ? blockIdx.x : blockIdx.x - nvBlocks;
    const int  M  = nv ? NV : NN;
    const unsigned short* WT = nv ? W1Tt : W1Tb;
    const int r0 = bi * 128;

    int maxRows = M - r0; if (maxRows > 128) maxRows = 128;
    const int maxB = maxRows << 8;          // valid bytes in this block's region

    // stage 128 rows fp32->bf16 (coalesced float4 stream / gather)
#pragma unroll
    for (int i = 0; i < 16; ++i) {
        int e = tid + 256 * i;
        int row = e >> 5, c4 = (e & 31) << 2;
        int r = r0 + row; if (r > M - 1) r = M - 1;
        int vr = nv ? r : vnodes[r];
        const float4 f = *(const float4*)(emb + (long)vr * D + c4);
        ushort4 h;
        h.x = f2bf(f.x); h.y = f2bf(f.y); h.z = f2bf(f.z); h.w = f2bf(f.w);
        *(ushort4*)(&sA[row][c4]) = h;
    }
    __syncthreads();

    // EB emission (pre-restage sA): fully-contiguous 4KB per instruction
    if (nv) {
        char* ebBase = (char*)(EB + (long)r0 * D);
#pragma unroll
        for (int j = 0; j < 8; ++j) {
            int p = j * 4096 + tid * 16;
            if (p < maxB) {
                int row = p >> 8, off = (p & 255) >> 1;
                *(bf16x8*)(ebBase + p) = *(const bf16x8*)(&sA[row][off]);
            }
        }
    }

    bf16x8 Bf[2][4];
#pragma unroll
    for (int nt = 0; nt < 2; ++nt)
#pragma unroll
        for (int kk = 0; kk < 4; ++kk)
            Bf[nt][kk] = *(const bf16x8*)(WT + (32 * w + 16 * nt + m) * D + kk * 32 + q * 8);
    float bv[2];
#pragma unroll
    for (int nt = 0; nt < 2; ++nt) bv[nt] = nv ? 0.f : b1[32 * w + 16 * nt + m];

    f32x4 acc[8][2];
#pragma unroll
    for (int mt = 0; mt < 8; ++mt)
#pragma unroll
        for (int nt = 0; nt < 2; ++nt) acc[mt][nt] = (f32x4){0.f, 0.f, 0.f, 0.f};

#pragma unroll
    for (int kk = 0; kk < 4; ++kk) {
#pragma unroll
        for (int mt = 0; mt < 8; ++mt) {
            bf16x8 a = *(const bf16x8*)(&sA[16 * mt + m][kk * 32 + q * 8]);
            acc[mt][0] = __builtin_amdgcn_mfma_f32_16x16x32_bf16(a, Bf[0][kk], acc[mt][0], 0, 0, 0);
            acc[mt][1] = __builtin_amdgcn_mfma_f32_16x16x32_bf16(a, Bf[1][kk], acc[mt][1], 0, 0, 0);
        }
    }

    // ---- restage C into sA, then fully-contiguous 4KB stores ----
    __syncthreads();   // all A-reads + EB-reads of sA complete
    // C/D layout: col=lane&15, row=(lane>>4)*4+reg
#pragma unroll
    for (int mt = 0; mt < 8; ++mt)
#pragma unroll
        for (int nt = 0; nt < 2; ++nt) {
            int col = 32 * w + 16 * nt + m;
#pragma unroll
            for (int r = 0; r < 4; ++r)
                sA[16 * mt + 4 * q + r][col] = f2bf(acc[mt][nt][r] + bv[nt]);
        }
    __syncthreads();
    {
        char* dstBase = (char*)((nv ? P1 : Q) + (long)r0 * D);
#pragma unroll
        for (int j = 0; j < 8; ++j) {
            int p = j * 4096 + tid * 16;
            if (p < maxB) {
                int row = p >> 8, off = (p & 255) >> 1;
                *(bf16x8*)(dstBase + p) = *(const bf16x8*)(&sA[row][off]);
            }
        }
    }
}

// Fused per-node aggregator (round-6-verified structure).
// Occupancy: __launch_bounds__(256,3) -> 3 blocks/CU (12 waves/CU).
// True reg footprint (round-6/7 evidence): ~104 VGPR + ~64 acc = ~168 unified
// regs; the (256,3) cap is 512/3 ~ 170 >= 168 (fits), while (256,4)'s 128-cap
// spilled 384MB (round 7). LDS: 3 x 37376 = 112KB < 160KB. Grid 768 = exactly
// the resident set.
__global__ __launch_bounds__(256, 3) void agg_kernel(
    const unsigned short* __restrict__ EB, const int* __restrict__ nidx,
    const unsigned short* __restrict__ W2T, const float* __restrict__ b2,
    const float* __restrict__ W3, const float* __restrict__ b3,
    const unsigned short* __restrict__ P1, const unsigned short* __restrict__ Q,
    float* __restrict__ out, int NN)
{
    __shared__ unsigned short sX[128][136];
    __shared__ float sSp[4][128];
    __shared__ float sAtt[128];

    const int tid  = threadIdx.x;
    const int lane = tid & 63;
    const int w    = tid >> 6;          // wave index == node sub-index
    const int m    = lane & 15, q = lane >> 4;
    const int g4   = q;                 // row-group within wave
    const int c    = m;                 // 16B chunk within row

    // register-resident B fragments (W2T), per-wave 32-col slice
    bf16x8 Bf[2][4];
#pragma unroll
    for (int nt = 0; nt < 2; ++nt)
#pragma unroll
        for (int kk = 0; kk < 4; ++kk)
            Bf[nt][kk] = *(const bf16x8*)(W2T + (32 * w + 16 * nt + m) * D + kk * 32 + q * 8);
    float b2v[2], w3v[2];
#pragma unroll
    for (int nt = 0; nt < 2; ++nt) {
        int col = 32 * w + 16 * nt + m;
        b2v[nt] = b2[col];
        w3v[nt] = W3[col];
    }
    const float b3s = b3[0];

    const int groups = (NN + 3) >> 2;

    // ---- pipeline prologue: group blockIdx.x ----
    int g = blockIdx.x;
    int ni[8];          // neighbor indices, k = 4j+g4 (uniform per 16-lane group)
    bf16x8 pf[8];       // P1 row fragments: pf[j] = P1[ni[j]][c*8 .. +8]
    if (g < groups) {
        int nd = g * 4 + w; if (nd > NN - 1) nd = NN - 1;
#pragma unroll
        for (int j = 0; j < 8; ++j) {
            ni[j] = nidx[nd * KN + 4 * j + g4];
            pf[j] = *(const bf16x8*)(P1 + (long)ni[j] * D + c * 8);
        }
    }

    for (; g < groups; g += gridDim.x) {
        const int node0 = g * 4;
        int nd = node0 + w; if (nd > NN - 1) nd = NN - 1;

        // ---- EB gather for current group at iteration top (4x256B/inst,
        //      consumed at iteration end: full iteration to hide) ----
        bf16x8 gv[8];
#pragma unroll
        for (int j = 0; j < 8; ++j)
            gv[j] = *(const bf16x8*)(EB + (long)ni[j] * D + c * 8);

        // ---- convert+store X = relu(pf + Q[nd]) into wave-private rows ----
        {
            const bf16x8 qv = *(const bf16x8*)(Q + (long)nd * D + c * 8);
#pragma unroll
            for (int j = 0; j < 8; ++j) {
                bf16x8 r;
#pragma unroll
                for (int h = 0; h < 8; ++h) {
                    float v = bf2f((unsigned short)pf[j][h]) + bf2f((unsigned short)qv[h]);
                    r[h] = (short)f2bf(v > 0.f ? v : 0.f);
                }
                *(bf16x8*)(&sX[w * 32 + 4 * j + g4][c * 8]) = r;
            }
        }

        // ---- next-group indices (same-address loads per 16-lane group) ----
        const int gn = g + gridDim.x;
        const bool more = gn < groups;
        int nin[8];
        if (more) {
            int ndn = gn * 4 + w; if (ndn > NN - 1) ndn = NN - 1;
#pragma unroll
            for (int j = 0; j < 8; ++j) nin[j] = nidx[ndn * KN + 4 * j + g4];
        }
        __syncthreads();   // sX ready for all waves

        // ---- P1 prefetch for NEXT group (in flight during compute) ----
        if (more) {
#pragma unroll
            for (int j = 0; j < 8; ++j)
                pf[j] = *(const bf16x8*)(P1 + (long)nin[j] * D + c * 8);
        }

        // ---- layer-2 GEMM in 2 halves of 4 M-tiles (acc = 32 regs) ----
#pragma unroll
        for (int hv = 0; hv < 2; ++hv) {
            f32x4 acc[4][2];
#pragma unroll
            for (int mt = 0; mt < 4; ++mt) {
                acc[mt][0] = (f32x4){0.f, 0.f, 0.f, 0.f};
                acc[mt][1] = (f32x4){0.f, 0.f, 0.f, 0.f};
            }
#pragma unroll
            for (int kk = 0; kk < 4; ++kk) {
#pragma unroll
                for (int mt = 0; mt < 4; ++mt) {
                    bf16x8 a = *(const bf16x8*)(&sX[16 * (4 * hv + mt) + m][kk * 32 + q * 8]);
                    acc[mt][0] = __builtin_amdgcn_mfma_f32_16x16x32_bf16(a, Bf[0][kk], acc[mt][0], 0, 0, 0);
                    acc[mt][1] = __builtin_amdgcn_mfma_f32_16x16x32_bf16(a, Bf[1][kk], acc[mt][1], 0, 0, 0);
                }
            }
            // scores for these 4 M-tiles: relu+bias, dot W3, reduce 16 lanes
#pragma unroll
            for (int mt = 0; mt < 4; ++mt) {
                float p[4];
#pragma unroll
                for (int r = 0; r < 4; ++r) {
                    float h0 = acc[mt][0][r] + b2v[0]; h0 = h0 > 0.f ? h0 : 0.f;
                    float h1 = acc[mt][1][r] + b2v[1]; h1 = h1 > 0.f ? h1 : 0.f;
                    p[r] = h0 * w3v[0] + h1 * w3v[1];
                }
#pragma unroll
                for (int off = 8; off >= 1; off >>= 1)
#pragma unroll
                    for (int r = 0; r < 4; ++r) p[r] += __shfl_xor(p[r], off, 16);
                if (m == 0) {
#pragma unroll
                    for (int r = 0; r < 4; ++r) sSp[w][16 * (4 * hv + mt) + 4 * q + r] = p[r];
                }
            }
        }
        __syncthreads();

        // ---- softmax: 128 scores = 4 nodes x 32 neighbors ----
        if (tid < 128) {
            float s = sSp[0][tid] + sSp[1][tid] + sSp[2][tid] + sSp[3][tid] + b3s;
            float mx = s;
#pragma unroll
            for (int off = 16; off >= 1; off >>= 1) mx = fmaxf(mx, __shfl_xor(mx, off, 32));
            float e = __expf(s - mx);
            float sum = e;
#pragma unroll
            for (int off = 16; off >= 1; off >>= 1) sum += __shfl_xor(sum, off, 32);
            sAtt[tid] = e / sum;
        }
        __syncthreads();

        // ---- aggregation: node w per wave, from top-issued gv ----
        {
            float r8[8] = {0.f, 0.f, 0.f, 0.f, 0.f, 0.f, 0.f, 0.f};
#pragma unroll
            for (int j = 0; j < 8; ++j) {
                float a = sAtt[w * KN + 4 * j + g4];
#pragma unroll
                for (int h = 0; h < 8; ++h)
                    r8[h] += a * bf2f((unsigned short)gv[j][h]);
            }
#pragma unroll
            for (int h = 0; h < 8; ++h) {
                r8[h] += __shfl_xor(r8[h], 16);
                r8[h] += __shfl_xor(r8[h], 32);
            }
            int ndw = node0 + w;
            if (g4 == 0 && ndw < NN) {
                float4 o0 = {r8[0], r8[1], r8[2], r8[3]};
                float4 o1 = {r8[4], r8[5], r8[6], r8[7]};
                *(float4*)(out + (long)ndw * D + c * 8)     = o0;
                *(float4*)(out + (long)ndw * D + c * 8 + 4) = o1;
            }
        }
        // carry next-group indices (safe: loop exits when !more)
#pragma unroll
        for (int j = 0; j < 8; ++j) ni[j] = nin[j];
    }
}

// Correct-but-slow fp32 VALU fallback (only if ws is too small).
__global__ __launch_bounds__(128) void naive_kernel(
    const float* __restrict__ emb, const int* __restrict__ vnodes,
    const int* __restrict__ nidx,
    const float* __restrict__ W1, const float* __restrict__ b1,
    const float* __restrict__ W2, const float* __restrict__ b2,
    const float* __restrict__ W3, const float* __restrict__ b3,
    float* __restrict__ out)
{
    __shared__ float sE[KN + 1][D];
    __shared__ float sH[KN][D];
    __shared__ float sH2[KN][D];
    __shared__ float sS[KN];
    __shared__ float sA2[KN];
    const int node = blockIdx.x, tid = threadIdx.x;

    for (int r = 0; r < KN + 1; ++r) {
        int vr = (r < KN) ? nidx[node * KN + r] : vnodes[node];
        sE[r][tid] = emb[(long)vr * D + tid];
    }
    __syncthreads();
    for (int k = 0; k < KN; ++k) {
        float s = b1[tid];
        for (int e = 0; e < D; ++e) s += sE[k][e]  * W1[e * D + tid];
        for (int e = 0; e < D; ++e) s += sE[KN][e] * W1[(D + e) * D + tid];
        sH[k][tid] = s > 0.f ? s : 0.f;
    }
    __syncthreads();
    for (int k = 0; k < KN; ++k) {
        float s = b2[tid];
        for (int e = 0; e < D; ++e) s += sH[k][e] * W2[e * D + tid];
        sH2[k][tid] = s > 0.f ? s : 0.f;
    }
    __syncthreads();
    if (tid < KN) {
        float s = b3[0];
        for (int e = 0; e < D; ++e) s += sH2[tid][e] * W3[e];
        sS[tid] = s;
    }
    __syncthreads();
    if (tid == 0) {
        float mx = sS[0];
        for (int k = 1; k < KN; ++k) mx = fmaxf(mx, sS[k]);
        float sum = 0.f;
        for (int k = 0; k < KN; ++k) { sA2[k] = __expf(sS[k] - mx); sum += sA2[k]; }
        for (int k = 0; k < KN; ++k) sA2[k] /= sum;
    }
    __syncthreads();
    float a = 0.f;
    for (int k = 0; k < KN; ++k) a += sA2[k] * sE[k][tid];
    out[(long)node * D + tid] = a;
}

extern "C" void kernel_launch(void* const* d_in, const int* in_sizes, int n_in,
                              void* d_out, int out_size, void* d_ws, size_t ws_size,
                              hipStream_t stream) {
    const float* emb    = (const float*)d_in[0];
    const int*   vnodes = (const int*)d_in[1];
    const int*   nidx   = (const int*)d_in[2];
    const float* W1     = (const float*)d_in[3];
    const float* b1     = (const float*)d_in[4];
    const float* W2     = (const float*)d_in[5];
    const float* b2     = (const float*)d_in[6];
    const float* W3     = (const float*)d_in[7];
    const float* b3     = (const float*)d_in[8];
    float* out = (float*)d_out;

    const int NV = in_sizes[0] / D;   // 200000
    const int NN = in_sizes[1];       // 20000

    const size_t p1_elems = (size_t)NV * D;
    const size_t q_elems  = (size_t)NN * D;
    const size_t wt_elems = (size_t)D * D;
    const size_t need = (2 * p1_elems + q_elems + 3 * wt_elems) * sizeof(unsigned short);

    if (ws_size >= need) {
        unsigned short* P1   = (unsigned short*)d_ws;
        unsigned short* Q    = P1 + p1_elems;
        unsigned short* W1Tt = Q + q_elems;
        unsigned short* W1Tb = W1Tt + wt_elems;
        unsigned short* W2T  = W1Tb + wt_elems;
        unsigned short* EB   = W2T + wt_elems;

        const int nvBlocks = (NV + 127) / 128;
        const int qBlocks  = (NN + 127) / 128;

        wt_kernel<<<(D * D + 255) / 256, 256, 0, stream>>>(W1, W2, W1Tt, W1Tb, W2T);
        p1q_kernel<<<nvBlocks + qBlocks, 256, 0, stream>>>(
            emb, vnodes, NV, NN, nvBlocks, W1Tt, W1Tb, b1, P1, Q, EB);
        agg_kernel<<<768, 256, 0, stream>>>(
            EB, nidx, W2T, b2, W3, b3, P1, Q, out, NN);
    } else {
        naive_kernel<<<NN, D, 0, stream>>>(emb, vnodes, nidx, W1, b1, W2, b2, W3, b3, out);
    }
}

// Round 9
// 273.792 us; speedup vs baseline: 1.4824x; 1.1340x over previous
//
#include <hip/hip_runtime.h>
#include <hip/hip_bf16.h>

#define D  128
#define KN 32

typedef __attribute__((ext_vector_type(8))) short bf16x8;
typedef __attribute__((ext_vector_type(4))) float f32x4;

static __device__ __forceinline__ unsigned short f2bf(float f) {
    union { float f; unsigned int u; } v; v.f = f;
    unsigned int u = v.u;
    u += 0x7fff + ((u >> 16) & 1);   // round-to-nearest-even
    return (unsigned short)(u >> 16);
}
static __device__ __forceinline__ float bf2f(unsigned short h) {
    union { float f; unsigned int u; } v; v.u = ((unsigned int)h) << 16;
    return v.f;
}

// One-shot: transpose+convert W1 halves and W2 into bf16 [col][k] layouts.
__global__ __launch_bounds__(256) void wt_kernel(
    const float* __restrict__ W1, const float* __restrict__ W2,
    unsigned short* __restrict__ W1Tt, unsigned short* __restrict__ W1Tb,
    unsigned short* __restrict__ W2T)
{
    int idx = blockIdx.x * 256 + threadIdx.x;
    if (idx < D * D) {
        int col = idx >> 7, e = idx & 127;
        W1Tt[col * D + e] = f2bf(W1[e * D + col]);
        W1Tb[col * D + e] = f2bf(W1[(D + e) * D + col]);
        W2T [col * D + e] = f2bf(W2[e * D + col]);
    }
}

// Fused P1/Q producer (round-3-verified version: restaged epilogue with
// fully-contiguous 4KB-per-instruction stores for EB, P1 and Q).
// Blocks [0,nvBlocks): P1 = emb@W1top (+ bf16 emb copy EB).
// Blocks [nvBlocks,..): Q = emb[vnodes]@W1bot + b1.
__global__ __launch_bounds__(256) void p1q_kernel(
    const float* __restrict__ emb, const int* __restrict__ vnodes,
    int NV, int NN, int nvBlocks,
    const unsigned short* __restrict__ W1Tt, const unsigned short* __restrict__ W1Tb,
    const float* __restrict__ b1,
    unsigned short* __restrict__ P1, unsigned short* __restrict__ Q,
    unsigned short* __restrict__ EB)
{
    __shared__ unsigned short sA[128][136];

    const int tid  = threadIdx.x;
    const int lane = tid & 63;
    const int w    = tid >> 6;
    const int m    = lane & 15, q = lane >> 4;

    const bool nv = (int)blockIdx.x < nvBlocks;
    const int  bi = nv ? blockIdx.x : blockIdx.x - nvBlocks;
    const int  M  = nv ? NV : NN;
    const unsigned short* WT = nv ? W1Tt : W1Tb;
    const int r0 = bi * 128;

    int maxRows = M - r0; if (maxRows > 128) maxRows = 128;
    const int maxB = maxRows << 8;          // valid bytes in this block's region

    // stage 128 rows fp32->bf16 (coalesced float4 stream / gather)
#pragma unroll
    for (int i = 0; i < 16; ++i) {
        int e = tid + 256 * i;
        int row = e >> 5, c4 = (e & 31) << 2;
        int r = r0 + row; if (r > M - 1) r = M - 1;
        int vr = nv ? r : vnodes[r];
        const float4 f = *(const float4*)(emb + (long)vr * D + c4);
        ushort4 h;
        h.x = f2bf(f.x); h.y = f2bf(f.y); h.z = f2bf(f.z); h.w = f2bf(f.w);
        *(ushort4*)(&sA[row][c4]) = h;
    }
    __syncthreads();

    // EB emission (pre-restage sA): fully-contiguous 4KB per instruction
    if (nv) {
        char* ebBase = (char*)(EB + (long)r0 * D);
#pragma unroll
        for (int j = 0; j < 8; ++j) {
            int p = j * 4096 + tid * 16;
            if (p < maxB) {
                int row = p >> 8, off = (p & 255) >> 1;
                *(bf16x8*)(ebBase + p) = *(const bf16x8*)(&sA[row][off]);
            }
        }
    }

    bf16x8 Bf[2][4];
#pragma unroll
    for (int nt = 0; nt < 2; ++nt)
#pragma unroll
        for (int kk = 0; kk < 4; ++kk)
            Bf[nt][kk] = *(const bf16x8*)(WT + (32 * w + 16 * nt + m) * D + kk * 32 + q * 8);
    float bv[2];
#pragma unroll
    for (int nt = 0; nt < 2; ++nt) bv[nt] = nv ? 0.f : b1[32 * w + 16 * nt + m];

    f32x4 acc[8][2];
#pragma unroll
    for (int mt = 0; mt < 8; ++mt)
#pragma unroll
        for (int nt = 0; nt < 2; ++nt) acc[mt][nt] = (f32x4){0.f, 0.f, 0.f, 0.f};

#pragma unroll
    for (int kk = 0; kk < 4; ++kk) {
#pragma unroll
        for (int mt = 0; mt < 8; ++mt) {
            bf16x8 a = *(const bf16x8*)(&sA[16 * mt + m][kk * 32 + q * 8]);
            acc[mt][0] = __builtin_amdgcn_mfma_f32_16x16x32_bf16(a, Bf[0][kk], acc[mt][0], 0, 0, 0);
            acc[mt][1] = __builtin_amdgcn_mfma_f32_16x16x32_bf16(a, Bf[1][kk], acc[mt][1], 0, 0, 0);
        }
    }

    // ---- restage C into sA, then fully-contiguous 4KB stores ----
    __syncthreads();   // all A-reads + EB-reads of sA complete
    // C/D layout: col=lane&15, row=(lane>>4)*4+reg
#pragma unroll
    for (int mt = 0; mt < 8; ++mt)
#pragma unroll
        for (int nt = 0; nt < 2; ++nt) {
            int col = 32 * w + 16 * nt + m;
#pragma unroll
            for (int r = 0; r < 4; ++r)
                sA[16 * mt + 4 * q + r][col] = f2bf(acc[mt][nt][r] + bv[nt]);
        }
    __syncthreads();
    {
        char* dstBase = (char*)((nv ? P1 : Q) + (long)r0 * D);
#pragma unroll
        for (int j = 0; j < 8; ++j) {
            int p = j * 4096 + tid * 16;
            if (p < maxB) {
                int row = p >> 8, off = (p & 255) >> 1;
                *(bf16x8*)(dstBase + p) = *(const bf16x8*)(&sA[row][off]);
            }
        }
    }
}

// Fused per-node aggregator (round-6 dataflow, register-phase-trimmed for
// 3 blocks/CU).
// Register plan vs round 6: the 32-reg gv (EB) gather no longer spans the
// GEMM window — it is issued AFTER the score phase (it depends only on ni,
// not on softmax), with sSp-write + softmax + barrier to hide latency plus
// 12 waves/CU of TLP. GEMM-phase live set ~ pf(32)+acc(32)+Bf(16)+ni/nin(16)
// + temps ~ 140 < 170-reg cap at (256,3). Round-8's spill (WRITE 120MB,
// VGPR squeezed 104->84) came from gv+pf+acc co-residency ~175.
// pf prefetch issues pre-barrier (pf dead after convert) to overlap the wait.
__global__ __launch_bounds__(256, 3) void agg_kernel(
    const unsigned short* __restrict__ EB, const int* __restrict__ nidx,
    const unsigned short* __restrict__ W2T, const float* __restrict__ b2,
    const float* __restrict__ W3, const float* __restrict__ b3,
    const unsigned short* __restrict__ P1, const unsigned short* __restrict__ Q,
    float* __restrict__ out, int NN)
{
    __shared__ unsigned short sX[128][136];
    __shared__ float sSp[4][128];
    __shared__ float sAtt[128];

    const int tid  = threadIdx.x;
    const int lane = tid & 63;
    const int w    = tid >> 6;          // wave index == node sub-index
    const int m    = lane & 15, q = lane >> 4;
    const int g4   = q;                 // row-group within wave
    const int c    = m;                 // 16B chunk within row

    // register-resident B fragments (W2T), per-wave 32-col slice
    bf16x8 Bf[2][4];
#pragma unroll
    for (int nt = 0; nt < 2; ++nt)
#pragma unroll
        for (int kk = 0; kk < 4; ++kk)
            Bf[nt][kk] = *(const bf16x8*)(W2T + (32 * w + 16 * nt + m) * D + kk * 32 + q * 8);
    float b2v[2], w3v[2];
#pragma unroll
    for (int nt = 0; nt < 2; ++nt) {
        int col = 32 * w + 16 * nt + m;
        b2v[nt] = b2[col];
        w3v[nt] = W3[col];
    }
    const float b3s = b3[0];

    const int groups = (NN + 3) >> 2;

    // ---- pipeline prologue: group blockIdx.x ----
    int g = blockIdx.x;
    int ni[8];          // neighbor indices, k = 4j+g4 (uniform per 16-lane group)
    bf16x8 pf[8];       // P1 row fragments: pf[j] = P1[ni[j]][c*8 .. +8]
    if (g < groups) {
        int nd = g * 4 + w; if (nd > NN - 1) nd = NN - 1;
#pragma unroll
        for (int j = 0; j < 8; ++j) {
            ni[j] = nidx[nd * KN + 4 * j + g4];
            pf[j] = *(const bf16x8*)(P1 + (long)ni[j] * D + c * 8);
        }
    }

    for (; g < groups; g += gridDim.x) {
        const int node0 = g * 4;
        int nd = node0 + w; if (nd > NN - 1) nd = NN - 1;

        // ---- convert+store X = relu(pf + Q[nd]) into wave-private rows ----
        {
            const bf16x8 qv = *(const bf16x8*)(Q + (long)nd * D + c * 8);
#pragma unroll
            for (int j = 0; j < 8; ++j) {
                bf16x8 r;
#pragma unroll
                for (int h = 0; h < 8; ++h) {
                    float v = bf2f((unsigned short)pf[j][h]) + bf2f((unsigned short)qv[h]);
                    r[h] = (short)f2bf(v > 0.f ? v : 0.f);
                }
                *(bf16x8*)(&sX[w * 32 + 4 * j + g4][c * 8]) = r;
            }
        }

        // ---- next-group indices (same-address loads per 16-lane group) ----
        const int gn = g + gridDim.x;
        const bool more = gn < groups;
        int nin[8];
        if (more) {
            int ndn = gn * 4 + w; if (ndn > NN - 1) ndn = NN - 1;
#pragma unroll
            for (int j = 0; j < 8; ++j) nin[j] = nidx[ndn * KN + 4 * j + g4];
        }

        // ---- P1 prefetch for NEXT group (pf dead after convert; issue
        //      pre-barrier so the loads run during the barrier wait) ----
        if (more) {
#pragma unroll
            for (int j = 0; j < 8; ++j)
                pf[j] = *(const bf16x8*)(P1 + (long)nin[j] * D + c * 8);
        }
        __syncthreads();   // sX ready for all waves

        // ---- layer-2 GEMM in 2 halves of 4 M-tiles (acc = 32 regs) ----
#pragma unroll
        for (int hv = 0; hv < 2; ++hv) {
            f32x4 acc[4][2];
#pragma unroll
            for (int mt = 0; mt < 4; ++mt) {
                acc[mt][0] = (f32x4){0.f, 0.f, 0.f, 0.f};
                acc[mt][1] = (f32x4){0.f, 0.f, 0.f, 0.f};
            }
#pragma unroll
            for (int kk = 0; kk < 4; ++kk) {
#pragma unroll
                for (int mt = 0; mt < 4; ++mt) {
                    bf16x8 a = *(const bf16x8*)(&sX[16 * (4 * hv + mt) + m][kk * 32 + q * 8]);
                    acc[mt][0] = __builtin_amdgcn_mfma_f32_16x16x32_bf16(a, Bf[0][kk], acc[mt][0], 0, 0, 0);
                    acc[mt][1] = __builtin_amdgcn_mfma_f32_16x16x32_bf16(a, Bf[1][kk], acc[mt][1], 0, 0, 0);
                }
            }
            // scores for these 4 M-tiles: relu+bias, dot W3, reduce 16 lanes
#pragma unroll
            for (int mt = 0; mt < 4; ++mt) {
                float p[4];
#pragma unroll
                for (int r = 0; r < 4; ++r) {
                    float h0 = acc[mt][0][r] + b2v[0]; h0 = h0 > 0.f ? h0 : 0.f;
                    float h1 = acc[mt][1][r] + b2v[1]; h1 = h1 > 0.f ? h1 : 0.f;
                    p[r] = h0 * w3v[0] + h1 * w3v[1];
                }
#pragma unroll
                for (int off = 8; off >= 1; off >>= 1)
#pragma unroll
                    for (int r = 0; r < 4; ++r) p[r] += __shfl_xor(p[r], off, 16);
                if (m == 0) {
#pragma unroll
                    for (int r = 0; r < 4; ++r) sSp[w][16 * (4 * hv + mt) + 4 * q + r] = p[r];
                }
            }
        }

        // ---- EB gather for current group (depends only on ni; issued here
        //      so it does NOT span the GEMM window; hidden behind softmax
        //      barrier + 12 waves/CU TLP) ----
        bf16x8 gv[8];
#pragma unroll
        for (int j = 0; j < 8; ++j)
            gv[j] = *(const bf16x8*)(EB + (long)ni[j] * D + c * 8);
        __syncthreads();

        // ---- softmax: 128 scores = 4 nodes x 32 neighbors ----
        if (tid < 128) {
            float s = sSp[0][tid] + sSp[1][tid] + sSp[2][tid] + sSp[3][tid] + b3s;
            float mx = s;
#pragma unroll
            for (int off = 16; off >= 1; off >>= 1) mx = fmaxf(mx, __shfl_xor(mx, off, 32));
            float e = __expf(s - mx);
            float sum = e;
#pragma unroll
            for (int off = 16; off >= 1; off >>= 1) sum += __shfl_xor(sum, off, 32);
            sAtt[tid] = e / sum;
        }
        __syncthreads();

        // ---- aggregation: node w per wave, from gv ----
        {
            float r8[8] = {0.f, 0.f, 0.f, 0.f, 0.f, 0.f, 0.f, 0.f};
#pragma unroll
            for (int j = 0; j < 8; ++j) {
                float a = sAtt[w * KN + 4 * j + g4];
#pragma unroll
                for (int h = 0; h < 8; ++h)
                    r8[h] += a * bf2f((unsigned short)gv[j][h]);
            }
#pragma unroll
            for (int h = 0; h < 8; ++h) {
                r8[h] += __shfl_xor(r8[h], 16);
                r8[h] += __shfl_xor(r8[h], 32);
            }
            int ndw = node0 + w;
            if (g4 == 0 && ndw < NN) {
                float4 o0 = {r8[0], r8[1], r8[2], r8[3]};
                float4 o1 = {r8[4], r8[5], r8[6], r8[7]};
                *(float4*)(out + (long)ndw * D + c * 8)     = o0;
                *(float4*)(out + (long)ndw * D + c * 8 + 4) = o1;
            }
        }
        // carry next-group indices (safe: loop exits when !more)
#pragma unroll
        for (int j = 0; j < 8; ++j) ni[j] = nin[j];
    }
}

// Correct-but-slow fp32 VALU fallback (only if ws is too small).
__global__ __launch_bounds__(128) void naive_kernel(
    const float* __restrict__ emb, const int* __restrict__ vnodes,
    const int* __restrict__ nidx,
    const float* __restrict__ W1, const float* __restrict__ b1,
    const float* __restrict__ W2, const float* __restrict__ b2,
    const float* __restrict__ W3, const float* __restrict__ b3,
    float* __restrict__ out)
{
    __shared__ float sE[KN + 1][D];
    __shared__ float sH[KN][D];
    __shared__ float sH2[KN][D];
    __shared__ float sS[KN];
    __shared__ float sA2[KN];
    const int node = blockIdx.x, tid = threadIdx.x;

    for (int r = 0; r < KN + 1; ++r) {
        int vr = (r < KN) ? nidx[node * KN + r] : vnodes[node];
        sE[r][tid] = emb[(long)vr * D + tid];
    }
    __syncthreads();
    for (int k = 0; k < KN; ++k) {
        float s = b1[tid];
        for (int e = 0; e < D; ++e) s += sE[k][e]  * W1[e * D + tid];
        for (int e = 0; e < D; ++e) s += sE[KN][e] * W1[(D + e) * D + tid];
        sH[k][tid] = s > 0.f ? s : 0.f;
    }
    __syncthreads();
    for (int k = 0; k < KN; ++k) {
        float s = b2[tid];
        for (int e = 0; e < D; ++e) s += sH[k][e] * W2[e * D + tid];
        sH2[k][tid] = s > 0.f ? s : 0.f;
    }
    __syncthreads();
    if (tid < KN) {
        float s = b3[0];
        for (int e = 0; e < D; ++e) s += sH2[tid][e] * W3[e];
        sS[tid] = s;
    }
    __syncthreads();
    if (tid == 0) {
        float mx = sS[0];
        for (int k = 1; k < KN; ++k) mx = fmaxf(mx, sS[k]);
        float sum = 0.f;
        for (int k = 0; k < KN; ++k) { sA2[k] = __expf(sS[k] - mx); sum += sA2[k]; }
        for (int k = 0; k < KN; ++k) sA2[k] /= sum;
    }
    __syncthreads();
    float a = 0.f;
    for (int k = 0; k < KN; ++k) a += sA2[k] * sE[k][tid];
    out[(long)node * D + tid] = a;
}

extern "C" void kernel_launch(void* const* d_in, const int* in_sizes, int n_in,
                              void* d_out, int out_size, void* d_ws, size_t ws_size,
                              hipStream_t stream) {
    const float* emb    = (const float*)d_in[0];
    const int*   vnodes = (const int*)d_in[1];
    const int*   nidx   = (const int*)d_in[2];
    const float* W1     = (const float*)d_in[3];
    const float* b1     = (const float*)d_in[4];
    const float* W2     = (const float*)d_in[5];
    const float* b2     = (const float*)d_in[6];
    const float* W3     = (const float*)d_in[7];
    const float* b3     = (const float*)d_in[8];
    float* out = (float*)d_out;

    const int NV = in_sizes[0] / D;   // 200000
    const int NN = in_sizes[1];       // 20000

    const size_t p1_elems = (size_t)NV * D;
    const size_t q_elems  = (size_t)NN * D;
    const size_t wt_elems = (size_t)D * D;
    const size_t need = (2 * p1_elems + q_elems + 3 * wt_elems) * sizeof(unsigned short);

    if (ws_size >= need) {
        unsigned short* P1   = (unsigned short*)d_ws;
        unsigned short* Q    = P1 + p1_elems;
        unsigned short* W1Tt = Q + q_elems;
        unsigned short* W1Tb = W1Tt + wt_elems;
        unsigned short* W2T  = W1Tb + wt_elems;
        unsigned short* EB   = W2T + wt_elems;

        const int nvBlocks = (NV + 127) / 128;
        const int qBlocks  = (NN + 127) / 128;

        wt_kernel<<<(D * D + 255) / 256, 256, 0, stream>>>(W1, W2, W1Tt, W1Tb, W2T);
        p1q_kernel<<<nvBlocks + qBlocks, 256, 0, stream>>>(
            emb, vnodes, NV, NN, nvBlocks, W1Tt, W1Tb, b1, P1, Q, EB);
        agg_kernel<<<768, 256, 0, stream>>>(
            EB, nidx, W2T, b2, W3, b3, P1, Q, out, NN);
    } else {
        naive_kernel<<<NN, D, 0, stream>>>(emb, vnodes, nidx, W1, b1, W2, b2, W3, b3, out);
    }
}